// Round 14
// baseline (242.420 us; speedup 1.0000x reference)
//
#include <hip/hip_runtime.h>
#include <hip/hip_fp16.h>
#include <math.h>

#define N_NODES   2000000
#define N_MOVABLE 1500000
#define N_FILLER  400000
#define N_NETS    1500000
#define N_PINS    (N_NETS * 4)          // 6,000,000
#define NB        512                   // bins per axis (cropped map)
#define NT        16                    // tiles per axis
#define TILE      32                    // bins per tile axis
#define NBUCKET   (NT * NT)             // 256 tile buckets
#define CAP       10240                 // tile slab capacity per bucket
#define NSLICE    4
#define NMAPS     NSLICE
#define NPB       4096                  // nets per gather block (4/thread)
#define RED_BLOCKS 1024

__device__ __forceinline__ int bin_idx(float v) {
    // BIN_W = 1000/512 = 1.953125 exactly; matches jnp floor(v / BIN_W)
    float b = floorf(v / 1.953125f);
    b = fminf(fmaxf(b, 0.0f), 511.0f);
    return (int)b;
}

// ---------------------------------------------------------------------------
// Stage 0: quantize+pack pins into ONE u32 per pin (xq | yq<<16, 1/64 unit).
// 24 MB array -> 16 pins/line -> partial per-XCD L2 reuse on the gather.
// Bin math stays exact: bin width = 125 quanta. Also zeroes ALL counters
// (ctrs[0..1023]: tile hist at 0, done ticket at 512) — strided loop since
// blockDim is 256.
// ---------------------------------------------------------------------------
__global__ __launch_bounds__(256)
void packq_kernel(const float* __restrict__ pin_pos,
                  unsigned* __restrict__ pxy,
                  unsigned* __restrict__ ctrs) {
    if (blockIdx.x == 0) {
        for (int j = threadIdx.x; j < 1024; j += 256) ctrs[j] = 0u;
    }
    int i = blockIdx.x * blockDim.x + threadIdx.x;
    if (i >= N_PINS / 4) return;
    float4 a = reinterpret_cast<const float4*>(pin_pos)[i];            // x[4i..]
    float4 b = reinterpret_cast<const float4*>(pin_pos + N_PINS)[i];   // y[4i..]
    uint4 o;
    o.x = __float2uint_rn(a.x * 64.0f) | (__float2uint_rn(b.x * 64.0f) << 16);
    o.y = __float2uint_rn(a.y * 64.0f) | (__float2uint_rn(b.y * 64.0f) << 16);
    o.z = __float2uint_rn(a.z * 64.0f) | (__float2uint_rn(b.z * 64.0f) << 16);
    o.w = __float2uint_rn(a.w * 64.0f) | (__float2uint_rn(b.w * 64.0f) << 16);
    reinterpret_cast<uint4*>(pxy)[i] = o;
}

// ---------------------------------------------------------------------------
// Per-net 8-byte tile record:
//   .x = f16x2 {vh, vv};  .y = blx | bly<<9 | spanx<<18 | spany<<23
// ---------------------------------------------------------------------------
__device__ __forceinline__ uint2 pack_tile_rec(float bw, float bh,
                                               unsigned blx, unsigned bhx,
                                               unsigned bly, unsigned bhy,
                                               int* tb) {
    float barea = fmaxf(bw * bh, 1e-6f);
    float vh = fminf((bw / barea) * (1.0f / 1.5f), 60000.0f);
    float vv = fminf((bh / barea) * (1.0f / 1.5f), 60000.0f);
    *tb = (int)((bly >> 5) * NT + (blx >> 5));
    __half2 h = __float22half2_rn(make_float2(vh, vv));
    uint2 r;
    r.x = *reinterpret_cast<unsigned*>(&h);
    r.y = blx | (bly << 9) | ((bhx + 1 - blx) << 18) | ((bhy + 1 - bly) << 23);
    return r;
}

// ---------------------------------------------------------------------------
// Stage 1: per-net gather (4 u32 gathers from 24 MB pxy) -> integer bbox ->
// tile record -> counting-sort into per-tile slabs. 4 nets/thread.
// ---------------------------------------------------------------------------
__global__ __launch_bounds__(1024)
void gather_bin_kernel(const unsigned* __restrict__ pxy,
                       const int* __restrict__ fnp,
                       uint2* __restrict__ slab,
                       unsigned* __restrict__ g_ptr) {
    __shared__ unsigned hist[NBUCKET];
    __shared__ unsigned hbase[NBUCKET];
    int t = threadIdx.x;
    if (t < NBUCKET) hist[t] = 0;
    __syncthreads();

    int n0 = blockIdx.x * NPB + t;
    bool v[4]; int4 fp[4]; uint2 r[4]; int b[4]; unsigned rk[4];
    #pragma unroll
    for (int k = 0; k < 4; ++k) {
        int n = n0 + k * 1024;
        v[k] = (n < N_NETS);
        fp[k] = v[k] ? *reinterpret_cast<const int4*>(fnp + 4 * (size_t)n)
                     : make_int4(0, 0, 0, 0);
    }
    #pragma unroll
    for (int k = 0; k < 4; ++k) {
        b[k] = 0;
        if (v[k]) {
            unsigned p0 = pxy[fp[k].x], p1 = pxy[fp[k].y];
            unsigned p2 = pxy[fp[k].z], p3 = pxy[fp[k].w];
            unsigned x0 = p0 & 0xffffu, y0 = p0 >> 16;
            unsigned x1 = p1 & 0xffffu, y1 = p1 >> 16;
            unsigned x2 = p2 & 0xffffu, y2 = p2 >> 16;
            unsigned x3 = p3 & 0xffffu, y3 = p3 >> 16;
            unsigned xl = min(min(x0, x1), min(x2, x3));
            unsigned xh = max(max(x0, x1), max(x2, x3));
            unsigned yl = min(min(y0, y1), min(y2, y3));
            unsigned yh = max(max(y0, y1), max(y2, y3));
            float bw = (float)(xh - xl) * 0.015625f;
            float bh = (float)(yh - yl) * 0.015625f;
            unsigned blx = min(xl / 125u, 511u), bhx = min(xh / 125u, 511u);
            unsigned bly = min(yl / 125u, 511u), bhy = min(yh / 125u, 511u);
            r[k] = pack_tile_rec(bw, bh, blx, bhx, bly, bhy, &b[k]);
        }
    }
    #pragma unroll
    for (int k = 0; k < 4; ++k) rk[k] = v[k] ? atomicAdd(&hist[b[k]], 1u) : 0u;
    __syncthreads();
    if (t < NBUCKET) {
        unsigned c = hist[t];
        hbase[t] = c ? atomicAdd(&g_ptr[t], c) : 0u;
    }
    __syncthreads();
    #pragma unroll
    for (int k = 0; k < 4; ++k) {
        if (v[k]) {
            unsigned s = hbase[b[k]] + rk[k];
            if (s < CAP) slab[(size_t)b[k] * CAP + s] = r[k];
        }
    }
}

// ---------------------------------------------------------------------------
// Fallback gather (tiny ws): direct f32 gather from pin_pos, f32 bins
// ---------------------------------------------------------------------------
__global__ __launch_bounds__(1024)
void gather_bin_f32_kernel(const float* __restrict__ pin_pos,
                           const int* __restrict__ fnp,
                           uint2* __restrict__ slab,
                           unsigned* __restrict__ g_ptr) {
    __shared__ unsigned hist[NBUCKET];
    __shared__ unsigned hbase[NBUCKET];
    int t = threadIdx.x;
    if (t < NBUCKET) hist[t] = 0;
    __syncthreads();

    int n0 = blockIdx.x * NPB + t;
    bool v[4]; uint2 r[4]; int b[4]; unsigned rk[4];
    #pragma unroll
    for (int k = 0; k < 4; ++k) {
        int n = n0 + k * 1024;
        v[k] = (n < N_NETS);
        b[k] = 0;
        if (v[k]) {
            int4 fp = *reinterpret_cast<const int4*>(fnp + 4 * (size_t)n);
            float px0 = pin_pos[fp.x], px1 = pin_pos[fp.y];
            float px2 = pin_pos[fp.z], px3 = pin_pos[fp.w];
            float py0 = pin_pos[N_PINS + fp.x], py1 = pin_pos[N_PINS + fp.y];
            float py2 = pin_pos[N_PINS + fp.z], py3 = pin_pos[N_PINS + fp.w];
            float xl = fminf(fminf(px0, px1), fminf(px2, px3));
            float xh = fmaxf(fmaxf(px0, px1), fmaxf(px2, px3));
            float yl = fminf(fminf(py0, py1), fminf(py2, py3));
            float yh = fmaxf(fmaxf(py0, py1), fmaxf(py2, py3));
            unsigned blx = bin_idx(xl), bhx = bin_idx(xh);
            unsigned bly = bin_idx(yl), bhy = bin_idx(yh);
            r[k] = pack_tile_rec(xh - xl, yh - yl, blx, bhx, bly, bhy, &b[k]);
        }
    }
    #pragma unroll
    for (int k = 0; k < 4; ++k) rk[k] = v[k] ? atomicAdd(&hist[b[k]], 1u) : 0u;
    __syncthreads();
    if (t < NBUCKET) {
        unsigned c = hist[t];
        hbase[t] = c ? atomicAdd(&g_ptr[t], c) : 0u;
    }
    __syncthreads();
    #pragma unroll
    for (int k = 0; k < 4; ++k) {
        if (v[k]) {
            unsigned s = hbase[b[k]] + rk[k];
            if (s < CAP) slab[(size_t)b[k] * CAP + s] = r[k];
        }
    }
}

// ---------------------------------------------------------------------------
// Tail: accum -> scanA -> scanB -> reduce(+last-block finish) -> final
// ---------------------------------------------------------------------------
__device__ __forceinline__ void rec_process(uint2 r, int x0, int y0,
                                            float2* acc) {
    float2 v = __half22float2(*reinterpret_cast<const __half2*>(&r.x));
    unsigned g = r.y;
    int ax0 = (int)(g & 511u);
    int ay0 = (int)((g >> 9) & 511u);
    int ax1 = ax0 + (int)((g >> 18) & 31u);
    int ay1 = ay0 + (int)((g >> 23) & 31u);
    int X0 = ax0 - x0, Y0 = ay0 - y0;
    int X1 = ax1 - x0, Y1 = ay1 - y0;
    bool iX0 = (unsigned)X0 < TILE, iX1 = (unsigned)X1 < TILE;
    bool iY0 = (unsigned)Y0 < TILE, iY1 = (unsigned)Y1 < TILE;
    if (iX0 && iY0) { atomicAdd(&acc[X0 * TILE + Y0].x,  v.x); atomicAdd(&acc[X0 * TILE + Y0].y,  v.y); }
    if (iX1 && iY0) { atomicAdd(&acc[X1 * TILE + Y0].x, -v.x); atomicAdd(&acc[X1 * TILE + Y0].y, -v.y); }
    if (iX0 && iY1) { atomicAdd(&acc[X0 * TILE + Y1].x, -v.x); atomicAdd(&acc[X0 * TILE + Y1].y, -v.y); }
    if (iX1 && iY1) { atomicAdd(&acc[X1 * TILE + Y1].x,  v.x); atomicAdd(&acc[X1 * TILE + Y1].y,  v.y); }
}

__global__ __launch_bounds__(256)
void accum_kernel(const uint2* __restrict__ slab,
                  const unsigned* __restrict__ g_cnt,
                  float2* __restrict__ Dp) {
    __shared__ float2 acc[TILE * TILE];
    int wg = blockIdx.x;
    int sl = wg & (NSLICE - 1), tile = wg >> 2;
    int tx = tile & (NT - 1), ty = tile >> 4;
    int tid = threadIdx.x;

    for (int i = tid; i < TILE * TILE; i += 256) acc[i] = make_float2(0.f, 0.f);
    __syncthreads();

    int x0 = tx * TILE, y0 = ty * TILE;
    #pragma unroll
    for (int dy = -1; dy <= 0; ++dy) {
        int sy = ty + dy; if (sy < 0) continue;
        #pragma unroll
        for (int dx = -1; dx <= 0; ++dx) {
            int sx = tx + dx; if (sx < 0) continue;
            int sb = sy * NT + sx;
            unsigned cnt = min(g_cnt[sb], (unsigned)CAP);
            unsigned lo = (cnt * (unsigned)sl) >> 2;
            unsigned hi = (cnt * (unsigned)(sl + 1)) >> 2;
            const uint2* recs = slab + (size_t)sb * CAP;
            unsigned i = lo + tid;
            for (; i + 768 < hi; i += 1024) {
                uint2 r0 = recs[i];
                uint2 r1 = recs[i + 256];
                uint2 r2 = recs[i + 512];
                uint2 r3 = recs[i + 768];
                rec_process(r0, x0, y0, acc);
                rec_process(r1, x0, y0, acc);
                rec_process(r2, x0, y0, acc);
                rec_process(r3, x0, y0, acc);
            }
            for (; i < hi; i += 256) rec_process(recs[i], x0, y0, acc);
        }
    }
    __syncthreads();

    float2* D = Dp + (size_t)sl * NB * NB;
    for (int i = tid; i < TILE * TILE; i += 256) {
        int X = i >> 5, Y = i & 31;
        D[(size_t)(x0 + X) * NB + (y0 + Y)] = acc[i];
    }
}

__global__ __launch_bounds__(512)
void scanA_kernel(const float2* __restrict__ Dp, float2* __restrict__ S) {
    __shared__ float2 s[NB];
    int x = blockIdx.x, t = threadIdx.x;
    float2 a = make_float2(0.f, 0.f);
    #pragma unroll
    for (int m = 0; m < NMAPS; ++m) {
        float2 v = Dp[(size_t)m * NB * NB + (size_t)x * NB + t];
        a.x += v.x; a.y += v.y;
    }
    s[t] = a;
    __syncthreads();
    for (int off = 1; off < NB; off <<= 1) {
        float2 u = s[t];
        if (t >= off) { float2 w = s[t - off]; u.x += w.x; u.y += w.y; }
        __syncthreads();
        s[t] = u;
        __syncthreads();
    }
    S[(size_t)x * NB + t] = s[t];
}

__global__ __launch_bounds__(512)
void scanB_kernel(float2* __restrict__ S) {
    __shared__ float2 s[NB];
    int y = blockIdx.x, t = threadIdx.x;
    s[t] = S[(size_t)t * NB + y];
    __syncthreads();
    for (int off = 1; off < NB; off <<= 1) {
        float2 u = s[t];
        if (t >= off) { float2 w = s[t - off]; u.x += w.x; u.y += w.y; }
        __syncthreads();
        s[t] = u;
        __syncthreads();
    }
    S[(size_t)t * NB + y] = s[t];
}

// reduce + last-block finish (look-back style ticket; deterministic: the
// last block sums partials in fixed index order).
__global__ __launch_bounds__(256)
void reduce_kernel(const float* __restrict__ pos,
                   const float* __restrict__ nsx,
                   const float* __restrict__ nsy,
                   const float2* __restrict__ S,
                   double* __restrict__ partials,
                   unsigned* __restrict__ done,
                   double* __restrict__ sums) {
    const int MQ = N_MOVABLE / 4;
    const int TQ = MQ + N_FILLER / 4;
    double a_old = 0.0, a_route = 0.0, a_fill = 0.0;
    int stride = gridDim.x * blockDim.x;
    for (int q = blockIdx.x * blockDim.x + threadIdx.x; q < TQ; q += stride) {
        if (q < MQ) {
            int i = 4 * q;
            float4 x4  = *reinterpret_cast<const float4*>(pos + i);
            float4 y4  = *reinterpret_cast<const float4*>(pos + N_NODES + i);
            float4 sx4 = *reinterpret_cast<const float4*>(nsx + i);
            float4 sy4 = *reinterpret_cast<const float4*>(nsy + i);
            float xs[4] = {x4.x, x4.y, x4.z, x4.w};
            float ys[4] = {y4.x, y4.y, y4.z, y4.w};
            float sxs[4] = {sx4.x, sx4.y, sx4.z, sx4.w};
            float sys[4] = {sy4.x, sy4.y, sy4.z, sy4.w};
            #pragma unroll
            for (int k = 0; k < 4; ++k) {
                int bx = bin_idx(xs[k] + 0.5f * sxs[k]);
                int by = bin_idx(ys[k] + 0.5f * sys[k]);
                float2 u2 = S[(size_t)bx * NB + by];
                float ratio = fminf(fmaxf(fmaxf(u2.x, u2.y), 0.5f), 2.0f);
                float area = sxs[k] * sys[k];
                a_old += (double)area;
                a_route += (double)(area * ratio);
            }
        } else {
            int j = (N_NODES - N_FILLER) + 4 * (q - MQ);
            float4 sx4 = *reinterpret_cast<const float4*>(nsx + j);
            float4 sy4 = *reinterpret_cast<const float4*>(nsy + j);
            a_fill += (double)(sx4.x * sy4.x + sx4.y * sy4.y +
                               sx4.z * sy4.z + sx4.w * sy4.w);
        }
    }
    for (int off = 32; off > 0; off >>= 1) {
        a_old   += __shfl_down(a_old, off);
        a_route += __shfl_down(a_route, off);
        a_fill  += __shfl_down(a_fill, off);
    }
    __shared__ double sd[4][3];
    __shared__ bool amLast;
    int wid = threadIdx.x >> 6, lane = threadIdx.x & 63;
    if (lane == 0) { sd[wid][0] = a_old; sd[wid][1] = a_route; sd[wid][2] = a_fill; }
    __syncthreads();
    if (threadIdx.x == 0) {
        double s0 = 0, s1 = 0, s2 = 0;
        for (int w = 0; w < 4; ++w) { s0 += sd[w][0]; s1 += sd[w][1]; s2 += sd[w][2]; }
        partials[blockIdx.x * 3 + 0] = s0;
        partials[blockIdx.x * 3 + 1] = s1;
        partials[blockIdx.x * 3 + 2] = s2;
        __threadfence();                               // release partials
        unsigned old = atomicAdd(done, 1u);            // device-scope ticket
        amLast = (old == gridDim.x - 1);
    }
    __syncthreads();
    if (!amLast) return;

    // Last block: acquire then sum all partials in fixed index order.
    __threadfence();
    int t = threadIdx.x;
    double s0 = 0, s1 = 0, s2 = 0;
    for (int r = t; r < RED_BLOCKS; r += 256) {
        s0 += partials[r * 3 + 0];
        s1 += partials[r * 3 + 1];
        s2 += partials[r * 3 + 2];
    }
    for (int off = 32; off > 0; off >>= 1) {
        s0 += __shfl_down(s0, off);
        s1 += __shfl_down(s1, off);
        s2 += __shfl_down(s2, off);
    }
    __syncthreads();   // sd reuse
    if (lane == 0) { sd[wid][0] = s0; sd[wid][1] = s1; sd[wid][2] = s2; }
    __syncthreads();
    if (t == 0) {
        double a = 0, b = 0, c = 0;
        for (int w = 0; w < 4; ++w) { a += sd[w][0]; b += sd[w][1]; c += sd[w][2]; }
        sums[0] = a; sums[1] = b; sums[2] = c;
        __threadfence();                               // release sums
    }
}

__global__ __launch_bounds__(256)
void final_kernel(const float* __restrict__ pos,
                  const float* __restrict__ nsx,
                  const float* __restrict__ nsy,
                  const float2* __restrict__ S,
                  const double* __restrict__ sums,
                  float* __restrict__ out) {
    double sum_area  = sums[0];
    double sum_route = sums[1];
    double fill_old  = sums[2];
    double max_total = sum_area + fill_old;

    float scale = fminf(1.0f, (float)(max_total / fmax(sum_route, 1e-6)));
    float sum_new = (float)(scale * (float)sum_route);
    float fscale = sqrtf(fmaxf((float)max_total - sum_new, 0.0f) /
                         fmaxf((float)fill_old, 1e-6f));

    int q = blockIdx.x * blockDim.x + threadIdx.x;
    if (q >= N_NODES / 4) return;
    int i = 4 * q;

    float4 x4  = *reinterpret_cast<const float4*>(pos + i);
    float4 y4  = *reinterpret_cast<const float4*>(pos + N_NODES + i);
    float4 sx4 = *reinterpret_cast<const float4*>(nsx + i);
    float4 sy4 = *reinterpret_cast<const float4*>(nsy + i);

    float xs[4] = {x4.x, x4.y, x4.z, x4.w};
    float ys[4] = {y4.x, y4.y, y4.z, y4.w};
    float sxs[4] = {sx4.x, sx4.y, sx4.z, sx4.w};
    float sys[4] = {sy4.x, sy4.y, sy4.z, sy4.w};

    if (i < N_MOVABLE) {
        #pragma unroll
        for (int k = 0; k < 4; ++k) {
            int bx = bin_idx(xs[k] + 0.5f * sxs[k]);
            int by = bin_idx(ys[k] + 0.5f * sys[k]);
            float2 u2 = S[(size_t)bx * NB + by];
            float ratio = fminf(fmaxf(fmaxf(u2.x, u2.y), 0.5f), 2.0f);
            float area = sxs[k] * sys[k];
            float new_area = area * ratio * scale;
            float sr = sqrtf(new_area / fmaxf(area, 1e-6f));
            float sx_new = sxs[k] * sr, sy_new = sys[k] * sr;
            xs[k] = xs[k] + 0.5f * (sxs[k] - sx_new);
            ys[k] = ys[k] + 0.5f * (sys[k] - sy_new);
            sxs[k] = sx_new; sys[k] = sy_new;
        }
    } else if (i >= N_NODES - N_FILLER) {
        #pragma unroll
        for (int k = 0; k < 4; ++k) { sxs[k] *= fscale; sys[k] *= fscale; }
    }

    *reinterpret_cast<float4*>(out + i)               = make_float4(xs[0], xs[1], xs[2], xs[3]);
    *reinterpret_cast<float4*>(out + N_NODES + i)     = make_float4(ys[0], ys[1], ys[2], ys[3]);
    *reinterpret_cast<float4*>(out + 2 * N_NODES + i) = make_float4(sxs[0], sxs[1], sxs[2], sxs[3]);
    *reinterpret_cast<float4*>(out + 3 * N_NODES + i) = make_float4(sys[0], sys[1], sys[2], sys[3]);
}

// ---------------------------------------------------------------------------
extern "C" void kernel_launch(void* const* d_in, const int* in_sizes, int n_in,
                              void* d_out, int out_size, void* d_ws, size_t ws_size,
                              hipStream_t stream) {
    const float* pos         = (const float*)d_in[0];
    const float* pin_pos     = (const float*)d_in[1];
    const float* nsx         = (const float*)d_in[2];
    const float* nsy         = (const float*)d_in[3];
    const int*   flat_netpin = (const int*)d_in[4];
    float* out = (float*)d_out;

    const size_t pxy_b   = (size_t)N_PINS * sizeof(unsigned);          // 24 MB
    const size_t tslab_b = (size_t)NBUCKET * CAP * sizeof(uint2);      // 20 MB
    const size_t ctr_b   = 4096;
    const size_t dp_b    = (size_t)NMAPS * NB * NB * sizeof(float2);   // 8 MB
    const size_t s_b     = (size_t)NB * NB * sizeof(float2);           // 2 MB
    const size_t part_b  = (size_t)RED_BLOCKS * 3 * sizeof(double);    // 24 KB

    // Primary: [pxy(24) | tslab(20) | ctrs]; tail overlays pxy
    // (dead after gather; dp+s+part+sums = ~10 MB <= 24 MB).
    const size_t need_primary = pxy_b + tslab_b + ctr_b;               // ~44 MB

    char* base = (char*)d_ws;
    bool primary = (ws_size >= need_primary);

    uint2* tslab; unsigned* ctrs; float2* Dp; float2* S;
    double* partials; double* sums;

    const int GB_BLOCKS = (N_NETS + NPB - 1) / NPB;    // 367

    if (primary) {
        unsigned* pxy = (unsigned*)base;
        tslab = (uint2*)(base + pxy_b);
        ctrs  = (unsigned*)(base + pxy_b + tslab_b);
        Dp       = (float2*)base;                       // overlay after gather
        S        = (float2*)(base + dp_b);
        partials = (double*)(base + dp_b + s_b);
        sums     = (double*)(base + dp_b + s_b + part_b);
        unsigned* g_tptr = ctrs;                        // [0..255]
        unsigned* done   = ctrs + 512;                  // zeroed by packq

        packq_kernel<<<(N_PINS / 4 + 255) / 256, 256, 0, stream>>>(
            pin_pos, pxy, ctrs);
        gather_bin_kernel<<<GB_BLOCKS, 1024, 0, stream>>>(
            pxy, flat_netpin, tslab, g_tptr);
        accum_kernel<<<NBUCKET * NSLICE, 256, 0, stream>>>(tslab, g_tptr, Dp);
        scanA_kernel <<<NB, 512, 0, stream>>>(Dp, S);
        scanB_kernel <<<NB, 512, 0, stream>>>(S);
        reduce_kernel<<<RED_BLOCKS, 256, 0, stream>>>(pos, nsx, nsy, S,
                                                      partials, done, sums);
        final_kernel <<<(N_NODES / 4 + 255) / 256, 256, 0, stream>>>(
            pos, nsx, nsy, S, sums, out);
    } else {
        tslab = (uint2*)base;
        Dp    = (float2*)(base + tslab_b);
        S     = (float2*)(base + tslab_b + dp_b);
        partials = (double*)(base + tslab_b + dp_b + s_b);
        sums     = (double*)(base + tslab_b + dp_b + s_b + part_b);
        ctrs     = (unsigned*)(base + tslab_b + dp_b + s_b + part_b + 64);
        unsigned* g_tptr = ctrs;
        unsigned* done   = ctrs + 512;

        hipMemsetAsync(ctrs, 0, 1024 * sizeof(unsigned), stream);
        gather_bin_f32_kernel<<<GB_BLOCKS, 1024, 0, stream>>>(
            pin_pos, flat_netpin, tslab, g_tptr);
        accum_kernel<<<NBUCKET * NSLICE, 256, 0, stream>>>(tslab, g_tptr, Dp);
        scanA_kernel <<<NB, 512, 0, stream>>>(Dp, S);
        scanB_kernel <<<NB, 512, 0, stream>>>(S);
        reduce_kernel<<<RED_BLOCKS, 256, 0, stream>>>(pos, nsx, nsy, S,
                                                      partials, done, sums);
        final_kernel <<<(N_NODES / 4 + 255) / 256, 256, 0, stream>>>(
            pos, nsx, nsy, S, sums, out);
    }
}

// Round 15
// 219.515 us; speedup vs baseline: 1.1043x; 1.1043x over previous
//
#include <hip/hip_runtime.h>
#include <hip/hip_fp16.h>
#include <math.h>

#define N_NODES   2000000
#define N_MOVABLE 1500000
#define N_FILLER  400000
#define N_NETS    1500000
#define N_PINS    (N_NETS * 4)          // 6,000,000
#define NB        512                   // bins per axis (cropped map)
#define NT        16                    // tiles per axis
#define TILE      32                    // bins per tile axis
#define NBUCKET   (NT * NT)             // 256 tile buckets
#define CAP       10240                 // tile slab capacity per bucket
#define NSLICE    4
#define NMAPS     NSLICE
#define NPB       4096                  // nets per gather block (4/thread)
#define RED_BLOCKS 1024

__device__ __forceinline__ int bin_idx(float v) {
    // BIN_W = 1000/512 = 1.953125 exactly; matches jnp floor(v / BIN_W)
    float b = floorf(v / 1.953125f);
    b = fminf(fmaxf(b, 0.0f), 511.0f);
    return (int)b;
}

// ---------------------------------------------------------------------------
// Stage 0: quantize+pack pins into ONE u32 per pin (xq | yq<<16, 1/64 unit).
// 24 MB array -> 16 pins/line -> partial per-XCD L2 reuse on the gather.
// Bin math stays exact: bin width = 125 quanta. Also zeroes counters.
// ---------------------------------------------------------------------------
__global__ __launch_bounds__(256)
void packq_kernel(const float* __restrict__ pin_pos,
                  unsigned* __restrict__ pxy,
                  unsigned* __restrict__ ctrs) {
    if (blockIdx.x == 0) {
        for (int j = threadIdx.x; j < 1024; j += 256) ctrs[j] = 0u;
    }
    int i = blockIdx.x * blockDim.x + threadIdx.x;
    if (i >= N_PINS / 4) return;
    float4 a = reinterpret_cast<const float4*>(pin_pos)[i];            // x[4i..]
    float4 b = reinterpret_cast<const float4*>(pin_pos + N_PINS)[i];   // y[4i..]
    uint4 o;
    o.x = __float2uint_rn(a.x * 64.0f) | (__float2uint_rn(b.x * 64.0f) << 16);
    o.y = __float2uint_rn(a.y * 64.0f) | (__float2uint_rn(b.y * 64.0f) << 16);
    o.z = __float2uint_rn(a.z * 64.0f) | (__float2uint_rn(b.z * 64.0f) << 16);
    o.w = __float2uint_rn(a.w * 64.0f) | (__float2uint_rn(b.w * 64.0f) << 16);
    reinterpret_cast<uint4*>(pxy)[i] = o;
}

// ---------------------------------------------------------------------------
// Per-net 8-byte tile record:
//   .x = f16x2 {vh, vv};  .y = blx | bly<<9 | spanx<<18 | spany<<23
// ---------------------------------------------------------------------------
__device__ __forceinline__ uint2 pack_tile_rec(float bw, float bh,
                                               unsigned blx, unsigned bhx,
                                               unsigned bly, unsigned bhy,
                                               int* tb) {
    float barea = fmaxf(bw * bh, 1e-6f);
    float vh = fminf((bw / barea) * (1.0f / 1.5f), 60000.0f);
    float vv = fminf((bh / barea) * (1.0f / 1.5f), 60000.0f);
    *tb = (int)((bly >> 5) * NT + (blx >> 5));
    __half2 h = __float22half2_rn(make_float2(vh, vv));
    uint2 r;
    r.x = *reinterpret_cast<unsigned*>(&h);
    r.y = blx | (bly << 9) | ((bhx + 1 - blx) << 18) | ((bhy + 1 - bly) << 23);
    return r;
}

// ---------------------------------------------------------------------------
// Stage 1: per-net gather (4 u32 gathers from 24 MB pxy) -> integer bbox ->
// tile record -> counting-sort into per-tile slabs. 4 nets/thread.
// ---------------------------------------------------------------------------
__global__ __launch_bounds__(1024)
void gather_bin_kernel(const unsigned* __restrict__ pxy,
                       const int* __restrict__ fnp,
                       uint2* __restrict__ slab,
                       unsigned* __restrict__ g_ptr) {
    __shared__ unsigned hist[NBUCKET];
    __shared__ unsigned hbase[NBUCKET];
    int t = threadIdx.x;
    if (t < NBUCKET) hist[t] = 0;
    __syncthreads();

    int n0 = blockIdx.x * NPB + t;
    bool v[4]; int4 fp[4]; uint2 r[4]; int b[4]; unsigned rk[4];
    #pragma unroll
    for (int k = 0; k < 4; ++k) {
        int n = n0 + k * 1024;
        v[k] = (n < N_NETS);
        fp[k] = v[k] ? *reinterpret_cast<const int4*>(fnp + 4 * (size_t)n)
                     : make_int4(0, 0, 0, 0);
    }
    #pragma unroll
    for (int k = 0; k < 4; ++k) {
        b[k] = 0;
        if (v[k]) {
            unsigned p0 = pxy[fp[k].x], p1 = pxy[fp[k].y];
            unsigned p2 = pxy[fp[k].z], p3 = pxy[fp[k].w];
            unsigned x0 = p0 & 0xffffu, y0 = p0 >> 16;
            unsigned x1 = p1 & 0xffffu, y1 = p1 >> 16;
            unsigned x2 = p2 & 0xffffu, y2 = p2 >> 16;
            unsigned x3 = p3 & 0xffffu, y3 = p3 >> 16;
            unsigned xl = min(min(x0, x1), min(x2, x3));
            unsigned xh = max(max(x0, x1), max(x2, x3));
            unsigned yl = min(min(y0, y1), min(y2, y3));
            unsigned yh = max(max(y0, y1), max(y2, y3));
            float bw = (float)(xh - xl) * 0.015625f;
            float bh = (float)(yh - yl) * 0.015625f;
            unsigned blx = min(xl / 125u, 511u), bhx = min(xh / 125u, 511u);
            unsigned bly = min(yl / 125u, 511u), bhy = min(yh / 125u, 511u);
            r[k] = pack_tile_rec(bw, bh, blx, bhx, bly, bhy, &b[k]);
        }
    }
    #pragma unroll
    for (int k = 0; k < 4; ++k) rk[k] = v[k] ? atomicAdd(&hist[b[k]], 1u) : 0u;
    __syncthreads();
    if (t < NBUCKET) {
        unsigned c = hist[t];
        hbase[t] = c ? atomicAdd(&g_ptr[t], c) : 0u;
    }
    __syncthreads();
    #pragma unroll
    for (int k = 0; k < 4; ++k) {
        if (v[k]) {
            unsigned s = hbase[b[k]] + rk[k];
            if (s < CAP) slab[(size_t)b[k] * CAP + s] = r[k];
        }
    }
}

// ---------------------------------------------------------------------------
// Fallback gather (tiny ws): direct f32 gather from pin_pos, f32 bins
// ---------------------------------------------------------------------------
__global__ __launch_bounds__(1024)
void gather_bin_f32_kernel(const float* __restrict__ pin_pos,
                           const int* __restrict__ fnp,
                           uint2* __restrict__ slab,
                           unsigned* __restrict__ g_ptr) {
    __shared__ unsigned hist[NBUCKET];
    __shared__ unsigned hbase[NBUCKET];
    int t = threadIdx.x;
    if (t < NBUCKET) hist[t] = 0;
    __syncthreads();

    int n0 = blockIdx.x * NPB + t;
    bool v[4]; uint2 r[4]; int b[4]; unsigned rk[4];
    #pragma unroll
    for (int k = 0; k < 4; ++k) {
        int n = n0 + k * 1024;
        v[k] = (n < N_NETS);
        b[k] = 0;
        if (v[k]) {
            int4 fp = *reinterpret_cast<const int4*>(fnp + 4 * (size_t)n);
            float px0 = pin_pos[fp.x], px1 = pin_pos[fp.y];
            float px2 = pin_pos[fp.z], px3 = pin_pos[fp.w];
            float py0 = pin_pos[N_PINS + fp.x], py1 = pin_pos[N_PINS + fp.y];
            float py2 = pin_pos[N_PINS + fp.z], py3 = pin_pos[N_PINS + fp.w];
            float xl = fminf(fminf(px0, px1), fminf(px2, px3));
            float xh = fmaxf(fmaxf(px0, px1), fmaxf(px2, px3));
            float yl = fminf(fminf(py0, py1), fminf(py2, py3));
            float yh = fmaxf(fmaxf(py0, py1), fmaxf(py2, py3));
            unsigned blx = bin_idx(xl), bhx = bin_idx(xh);
            unsigned bly = bin_idx(yl), bhy = bin_idx(yh);
            r[k] = pack_tile_rec(xh - xl, yh - yl, blx, bhx, bly, bhy, &b[k]);
        }
    }
    #pragma unroll
    for (int k = 0; k < 4; ++k) rk[k] = v[k] ? atomicAdd(&hist[b[k]], 1u) : 0u;
    __syncthreads();
    if (t < NBUCKET) {
        unsigned c = hist[t];
        hbase[t] = c ? atomicAdd(&g_ptr[t], c) : 0u;
    }
    __syncthreads();
    #pragma unroll
    for (int k = 0; k < 4; ++k) {
        if (v[k]) {
            unsigned s = hbase[b[k]] + rk[k];
            if (s < CAP) slab[(size_t)b[k] * CAP + s] = r[k];
        }
    }
}

// ---------------------------------------------------------------------------
// Tail (proven, r12 config): accum -> scanA -> scanB -> reduce -> finish -> final
// ---------------------------------------------------------------------------
__device__ __forceinline__ void rec_process(uint2 r, int x0, int y0,
                                            float2* acc) {
    float2 v = __half22float2(*reinterpret_cast<const __half2*>(&r.x));
    unsigned g = r.y;
    int ax0 = (int)(g & 511u);
    int ay0 = (int)((g >> 9) & 511u);
    int ax1 = ax0 + (int)((g >> 18) & 31u);
    int ay1 = ay0 + (int)((g >> 23) & 31u);
    int X0 = ax0 - x0, Y0 = ay0 - y0;
    int X1 = ax1 - x0, Y1 = ay1 - y0;
    bool iX0 = (unsigned)X0 < TILE, iX1 = (unsigned)X1 < TILE;
    bool iY0 = (unsigned)Y0 < TILE, iY1 = (unsigned)Y1 < TILE;
    if (iX0 && iY0) { atomicAdd(&acc[X0 * TILE + Y0].x,  v.x); atomicAdd(&acc[X0 * TILE + Y0].y,  v.y); }
    if (iX1 && iY0) { atomicAdd(&acc[X1 * TILE + Y0].x, -v.x); atomicAdd(&acc[X1 * TILE + Y0].y, -v.y); }
    if (iX0 && iY1) { atomicAdd(&acc[X0 * TILE + Y1].x, -v.x); atomicAdd(&acc[X0 * TILE + Y1].y, -v.y); }
    if (iX1 && iY1) { atomicAdd(&acc[X1 * TILE + Y1].x,  v.x); atomicAdd(&acc[X1 * TILE + Y1].y,  v.y); }
}

__global__ __launch_bounds__(256)
void accum_kernel(const uint2* __restrict__ slab,
                  const unsigned* __restrict__ g_cnt,
                  float2* __restrict__ Dp) {
    __shared__ float2 acc[TILE * TILE];
    int wg = blockIdx.x;
    int sl = wg & (NSLICE - 1), tile = wg >> 2;
    int tx = tile & (NT - 1), ty = tile >> 4;
    int tid = threadIdx.x;

    for (int i = tid; i < TILE * TILE; i += 256) acc[i] = make_float2(0.f, 0.f);
    __syncthreads();

    int x0 = tx * TILE, y0 = ty * TILE;
    #pragma unroll
    for (int dy = -1; dy <= 0; ++dy) {
        int sy = ty + dy; if (sy < 0) continue;
        #pragma unroll
        for (int dx = -1; dx <= 0; ++dx) {
            int sx = tx + dx; if (sx < 0) continue;
            int sb = sy * NT + sx;
            unsigned cnt = min(g_cnt[sb], (unsigned)CAP);
            unsigned lo = (cnt * (unsigned)sl) >> 2;
            unsigned hi = (cnt * (unsigned)(sl + 1)) >> 2;
            const uint2* recs = slab + (size_t)sb * CAP;
            unsigned i = lo + tid;
            for (; i + 768 < hi; i += 1024) {
                uint2 r0 = recs[i];
                uint2 r1 = recs[i + 256];
                uint2 r2 = recs[i + 512];
                uint2 r3 = recs[i + 768];
                rec_process(r0, x0, y0, acc);
                rec_process(r1, x0, y0, acc);
                rec_process(r2, x0, y0, acc);
                rec_process(r3, x0, y0, acc);
            }
            for (; i < hi; i += 256) rec_process(recs[i], x0, y0, acc);
        }
    }
    __syncthreads();

    float2* D = Dp + (size_t)sl * NB * NB;
    for (int i = tid; i < TILE * TILE; i += 256) {
        int X = i >> 5, Y = i & 31;
        D[(size_t)(x0 + X) * NB + (y0 + Y)] = acc[i];
    }
}

__global__ __launch_bounds__(512)
void scanA_kernel(const float2* __restrict__ Dp, float2* __restrict__ S) {
    __shared__ float2 s[NB];
    int x = blockIdx.x, t = threadIdx.x;
    float2 a = make_float2(0.f, 0.f);
    #pragma unroll
    for (int m = 0; m < NMAPS; ++m) {
        float2 v = Dp[(size_t)m * NB * NB + (size_t)x * NB + t];
        a.x += v.x; a.y += v.y;
    }
    s[t] = a;
    __syncthreads();
    for (int off = 1; off < NB; off <<= 1) {
        float2 u = s[t];
        if (t >= off) { float2 w = s[t - off]; u.x += w.x; u.y += w.y; }
        __syncthreads();
        s[t] = u;
        __syncthreads();
    }
    S[(size_t)x * NB + t] = s[t];
}

__global__ __launch_bounds__(512)
void scanB_kernel(float2* __restrict__ S) {
    __shared__ float2 s[NB];
    int y = blockIdx.x, t = threadIdx.x;
    s[t] = S[(size_t)t * NB + y];
    __syncthreads();
    for (int off = 1; off < NB; off <<= 1) {
        float2 u = s[t];
        if (t >= off) { float2 w = s[t - off]; u.x += w.x; u.y += w.y; }
        __syncthreads();
        s[t] = u;
        __syncthreads();
    }
    S[(size_t)t * NB + y] = s[t];
}

__global__ __launch_bounds__(256)
void reduce_kernel(const float* __restrict__ pos,
                   const float* __restrict__ nsx,
                   const float* __restrict__ nsy,
                   const float2* __restrict__ S,
                   double* __restrict__ partials) {
    const int MQ = N_MOVABLE / 4;
    const int TQ = MQ + N_FILLER / 4;
    double a_old = 0.0, a_route = 0.0, a_fill = 0.0;
    int stride = gridDim.x * blockDim.x;
    for (int q = blockIdx.x * blockDim.x + threadIdx.x; q < TQ; q += stride) {
        if (q < MQ) {
            int i = 4 * q;
            float4 x4  = *reinterpret_cast<const float4*>(pos + i);
            float4 y4  = *reinterpret_cast<const float4*>(pos + N_NODES + i);
            float4 sx4 = *reinterpret_cast<const float4*>(nsx + i);
            float4 sy4 = *reinterpret_cast<const float4*>(nsy + i);
            float xs[4] = {x4.x, x4.y, x4.z, x4.w};
            float ys[4] = {y4.x, y4.y, y4.z, y4.w};
            float sxs[4] = {sx4.x, sx4.y, sx4.z, sx4.w};
            float sys[4] = {sy4.x, sy4.y, sy4.z, sy4.w};
            #pragma unroll
            for (int k = 0; k < 4; ++k) {
                int bx = bin_idx(xs[k] + 0.5f * sxs[k]);
                int by = bin_idx(ys[k] + 0.5f * sys[k]);
                float2 u2 = S[(size_t)bx * NB + by];
                float ratio = fminf(fmaxf(fmaxf(u2.x, u2.y), 0.5f), 2.0f);
                float area = sxs[k] * sys[k];
                a_old += (double)area;
                a_route += (double)(area * ratio);
            }
        } else {
            int j = (N_NODES - N_FILLER) + 4 * (q - MQ);
            float4 sx4 = *reinterpret_cast<const float4*>(nsx + j);
            float4 sy4 = *reinterpret_cast<const float4*>(nsy + j);
            a_fill += (double)(sx4.x * sy4.x + sx4.y * sy4.y +
                               sx4.z * sy4.z + sx4.w * sy4.w);
        }
    }
    for (int off = 32; off > 0; off >>= 1) {
        a_old   += __shfl_down(a_old, off);
        a_route += __shfl_down(a_route, off);
        a_fill  += __shfl_down(a_fill, off);
    }
    __shared__ double sd[4][3];
    int wid = threadIdx.x >> 6, lane = threadIdx.x & 63;
    if (lane == 0) { sd[wid][0] = a_old; sd[wid][1] = a_route; sd[wid][2] = a_fill; }
    __syncthreads();
    if (threadIdx.x == 0) {
        double s0 = 0, s1 = 0, s2 = 0;
        for (int w = 0; w < 4; ++w) { s0 += sd[w][0]; s1 += sd[w][1]; s2 += sd[w][2]; }
        partials[blockIdx.x * 3 + 0] = s0;
        partials[blockIdx.x * 3 + 1] = s1;
        partials[blockIdx.x * 3 + 2] = s2;
    }
}

__global__ __launch_bounds__(256)
void finish_kernel(const double* __restrict__ partials,
                   double* __restrict__ sums) {
    int t = threadIdx.x;
    double s0 = 0, s1 = 0, s2 = 0;
    for (int r = t; r < RED_BLOCKS; r += 256) {
        s0 += partials[r * 3 + 0];
        s1 += partials[r * 3 + 1];
        s2 += partials[r * 3 + 2];
    }
    for (int off = 32; off > 0; off >>= 1) {
        s0 += __shfl_down(s0, off);
        s1 += __shfl_down(s1, off);
        s2 += __shfl_down(s2, off);
    }
    __shared__ double sd[4][3];
    int wid = t >> 6, lane = t & 63;
    if (lane == 0) { sd[wid][0] = s0; sd[wid][1] = s1; sd[wid][2] = s2; }
    __syncthreads();
    if (t == 0) {
        double a = 0, b = 0, c = 0;
        for (int w = 0; w < 4; ++w) { a += sd[w][0]; b += sd[w][1]; c += sd[w][2]; }
        sums[0] = a; sums[1] = b; sums[2] = c;
    }
}

__global__ __launch_bounds__(256)
void final_kernel(const float* __restrict__ pos,
                  const float* __restrict__ nsx,
                  const float* __restrict__ nsy,
                  const float2* __restrict__ S,
                  const double* __restrict__ sums,
                  float* __restrict__ out) {
    double sum_area  = sums[0];
    double sum_route = sums[1];
    double fill_old  = sums[2];
    double max_total = sum_area + fill_old;

    float scale = fminf(1.0f, (float)(max_total / fmax(sum_route, 1e-6)));
    float sum_new = (float)(scale * (float)sum_route);
    float fscale = sqrtf(fmaxf((float)max_total - sum_new, 0.0f) /
                         fmaxf((float)fill_old, 1e-6f));

    int q = blockIdx.x * blockDim.x + threadIdx.x;
    if (q >= N_NODES / 4) return;
    int i = 4 * q;

    float4 x4  = *reinterpret_cast<const float4*>(pos + i);
    float4 y4  = *reinterpret_cast<const float4*>(pos + N_NODES + i);
    float4 sx4 = *reinterpret_cast<const float4*>(nsx + i);
    float4 sy4 = *reinterpret_cast<const float4*>(nsy + i);

    float xs[4] = {x4.x, x4.y, x4.z, x4.w};
    float ys[4] = {y4.x, y4.y, y4.z, y4.w};
    float sxs[4] = {sx4.x, sx4.y, sx4.z, sx4.w};
    float sys[4] = {sy4.x, sy4.y, sy4.z, sy4.w};

    if (i < N_MOVABLE) {
        #pragma unroll
        for (int k = 0; k < 4; ++k) {
            int bx = bin_idx(xs[k] + 0.5f * sxs[k]);
            int by = bin_idx(ys[k] + 0.5f * sys[k]);
            float2 u2 = S[(size_t)bx * NB + by];
            float ratio = fminf(fmaxf(fmaxf(u2.x, u2.y), 0.5f), 2.0f);
            float area = sxs[k] * sys[k];
            float new_area = area * ratio * scale;
            float sr = sqrtf(new_area / fmaxf(area, 1e-6f));
            float sx_new = sxs[k] * sr, sy_new = sys[k] * sr;
            xs[k] = xs[k] + 0.5f * (sxs[k] - sx_new);
            ys[k] = ys[k] + 0.5f * (sys[k] - sy_new);
            sxs[k] = sx_new; sys[k] = sy_new;
        }
    } else if (i >= N_NODES - N_FILLER) {
        #pragma unroll
        for (int k = 0; k < 4; ++k) { sxs[k] *= fscale; sys[k] *= fscale; }
    }

    *reinterpret_cast<float4*>(out + i)               = make_float4(xs[0], xs[1], xs[2], xs[3]);
    *reinterpret_cast<float4*>(out + N_NODES + i)     = make_float4(ys[0], ys[1], ys[2], ys[3]);
    *reinterpret_cast<float4*>(out + 2 * N_NODES + i) = make_float4(sxs[0], sxs[1], sxs[2], sxs[3]);
    *reinterpret_cast<float4*>(out + 3 * N_NODES + i) = make_float4(sys[0], sys[1], sys[2], sys[3]);
}

// ---------------------------------------------------------------------------
extern "C" void kernel_launch(void* const* d_in, const int* in_sizes, int n_in,
                              void* d_out, int out_size, void* d_ws, size_t ws_size,
                              hipStream_t stream) {
    const float* pos         = (const float*)d_in[0];
    const float* pin_pos     = (const float*)d_in[1];
    const float* nsx         = (const float*)d_in[2];
    const float* nsy         = (const float*)d_in[3];
    const int*   flat_netpin = (const int*)d_in[4];
    float* out = (float*)d_out;

    const size_t pxy_b   = (size_t)N_PINS * sizeof(unsigned);          // 24 MB
    const size_t tslab_b = (size_t)NBUCKET * CAP * sizeof(uint2);      // 20 MB
    const size_t ctr_b   = 4096;
    const size_t dp_b    = (size_t)NMAPS * NB * NB * sizeof(float2);   // 8 MB
    const size_t s_b     = (size_t)NB * NB * sizeof(float2);           // 2 MB
    const size_t part_b  = (size_t)RED_BLOCKS * 3 * sizeof(double);    // 24 KB

    // Primary: [pxy(24) | tslab(20) | ctrs]; tail overlays pxy
    // (dead after gather; dp+s+part+sums = ~10 MB <= 24 MB).
    const size_t need_primary = pxy_b + tslab_b + ctr_b;               // ~44 MB

    char* base = (char*)d_ws;
    bool primary = (ws_size >= need_primary);

    uint2* tslab; unsigned* ctrs; float2* Dp; float2* S;
    double* partials; double* sums;

    const int GB_BLOCKS = (N_NETS + NPB - 1) / NPB;    // 367

    if (primary) {
        unsigned* pxy = (unsigned*)base;
        tslab = (uint2*)(base + pxy_b);
        ctrs  = (unsigned*)(base + pxy_b + tslab_b);
        Dp       = (float2*)base;                       // overlay after gather
        S        = (float2*)(base + dp_b);
        partials = (double*)(base + dp_b + s_b);
        sums     = (double*)(base + dp_b + s_b + part_b);
        unsigned* g_tptr = ctrs;

        packq_kernel<<<(N_PINS / 4 + 255) / 256, 256, 0, stream>>>(
            pin_pos, pxy, ctrs);
        gather_bin_kernel<<<GB_BLOCKS, 1024, 0, stream>>>(
            pxy, flat_netpin, tslab, g_tptr);
        accum_kernel<<<NBUCKET * NSLICE, 256, 0, stream>>>(tslab, g_tptr, Dp);
    } else {
        tslab = (uint2*)base;
        Dp    = (float2*)(base + tslab_b);
        S     = (float2*)(base + tslab_b + dp_b);
        partials = (double*)(base + tslab_b + dp_b + s_b);
        sums     = (double*)(base + tslab_b + dp_b + s_b + part_b);
        ctrs     = (unsigned*)(base + tslab_b + dp_b + s_b + part_b + 64);
        unsigned* g_tptr = ctrs;

        hipMemsetAsync(ctrs, 0, 1024 * sizeof(unsigned), stream);
        gather_bin_f32_kernel<<<GB_BLOCKS, 1024, 0, stream>>>(
            pin_pos, flat_netpin, tslab, g_tptr);
        accum_kernel<<<NBUCKET * NSLICE, 256, 0, stream>>>(tslab, g_tptr, Dp);
    }

    scanA_kernel <<<NB, 512, 0, stream>>>(Dp, S);
    scanB_kernel <<<NB, 512, 0, stream>>>(S);
    reduce_kernel<<<RED_BLOCKS, 256, 0, stream>>>(pos, nsx, nsy, S, partials);
    finish_kernel<<<1, 256, 0, stream>>>(partials, sums);
    final_kernel <<<(N_NODES / 4 + 255) / 256, 256, 0, stream>>>(pos, nsx, nsy, S, sums, out);
}